// Round 1
// baseline (389.948 us; speedup 1.0000x reference)
//
#include <hip/hip_runtime.h>

#define PI_D 3.14159265358979323846
#define PI_F 3.14159265358979323846f
#define NP 7

// ---- workspace layout (floats) ----
// Y01 @ 0          : 16*256*256 = 1048576
// Y02 @ 1048576    : 1048576
// Y12 @ 2097152    : 16*128*128 = 262144
// T   @ 2359296    : 1048576
// R01 @ 3407872    : 256
// R02 @ 3408128    : 256
// R12 @ 3408384    : 128
// S01 @ 3408512    : 64 (16ch x 4)
// S02 @ 3408576    : 64
// S12 @ 3408640    : 64   -> total 3408704 floats ~= 13.0 MB

__device__ inline float rtab_val(int n, int m2, int t) {
  if (t == 0) return 1.0f;
  double th = PI_D * (double)t / (double)n;
  double v = sin(th * (double)(m2 - 1)) / sin(th) + cos(th * (double)m2);
  return (float)(v / (double)m2);  // scaled by 1/m2 (applied once per axis)
}

__global__ void k_tables(float* __restrict__ R01, float* __restrict__ R02,
                         float* __restrict__ R12) {
  int t = threadIdx.x;
  if (t < 256) {
    R01[t] = rtab_val(256, 128, t);
    R02[t] = rtab_val(256, 64, t);
  }
  if (t < 128) R12[t] = rtab_val(128, 64, t);
}

// Nyquist-correction projections: Scc,Scs,Ssc,Sss per channel
__global__ void k_proj(const float* __restrict__ X, int lg, int s,
                       float* __restrict__ S) {
  int ch = blockIdx.x;
  int n = 1 << lg;
  int total = n * n;
  const float* x = X + (size_t)ch * total;
  float a = PI_F / (float)s;
  int per = 2 * s;
  float cc = 0.f, cs = 0.f, sc = 0.f, ss = 0.f;
  for (int idx = threadIdx.x; idx < total; idx += 256) {
    int mx = idx >> lg;
    int my = idx & (n - 1);
    float sxv, cxv, syv, cyv;
    sincosf(a * (float)(mx & (per - 1)), &sxv, &cxv);
    sincosf(a * (float)(my & (per - 1)), &syv, &cyv);
    float v = x[idx];
    cc += v * cxv * cyv;
    cs += v * cxv * syv;
    sc += v * sxv * cyv;
    ss += v * sxv * syv;
  }
  __shared__ float red[256];
  float vals[4] = {cc, cs, sc, ss};
#pragma unroll
  for (int j = 0; j < 4; ++j) {
    red[threadIdx.x] = vals[j];
    __syncthreads();
    for (int st = 128; st > 0; st >>= 1) {
      if (threadIdx.x < st) red[threadIdx.x] += red[threadIdx.x + st];
      __syncthreads();
    }
    if (threadIdx.x == 0) S[ch * 4 + j] = red[0];
    __syncthreads();
  }
}

// circular conv along contiguous (last) axis: T[row, t] = sum_my R[(t-my)&(N-1)] * In[row, my]
template <int N>
__global__ __launch_bounds__(N) void k_conv1(const float* __restrict__ In,
                                             float* __restrict__ Out,
                                             const float* __restrict__ Rt) {
  __shared__ float Rl[N];
  __shared__ float Xl[4][N];
  int t = threadIdx.x;
  size_t row0 = (size_t)blockIdx.x * 4;
  Rl[t] = Rt[t];
#pragma unroll
  for (int r = 0; r < 4; ++r) Xl[r][t] = In[(row0 + r) * N + t];
  __syncthreads();
  float a0 = 0.f, a1 = 0.f, a2 = 0.f, a3 = 0.f;
#pragma unroll 4
  for (int my = 0; my < N; ++my) {
    float rv = Rl[(t - my) & (N - 1)];
    a0 += rv * Xl[0][my];
    a1 += rv * Xl[1][my];
    a2 += rv * Xl[2][my];
    a3 += rv * Xl[3][my];
  }
  Out[(row0 + 0) * N + t] = a0;
  Out[(row0 + 1) * N + t] = a1;
  Out[(row0 + 2) * N + t] = a2;
  Out[(row0 + 3) * N + t] = a3;
}

// circular conv along first axis of each NxN channel matrix + Nyquist-correction epilogue
template <int N, int S>
__global__ __launch_bounds__(256) void k_conv2(const float* __restrict__ T,
                                               float* __restrict__ Y,
                                               const float* __restrict__ Rt,
                                               const float* __restrict__ Sc,
                                               float inv) {
  __shared__ float Rl[N];
  __shared__ float Tl[64][65];
  int tid = threadIdx.x;
  int tyt = tid & 15;
  int txt = tid >> 4;
  int txTile = blockIdx.x * 64;
  int tyTile = blockIdx.y * 64;
  int ch = blockIdx.z;
  const float* Tc = T + (size_t)ch * N * N;
  for (int i = tid; i < N; i += 256) Rl[i] = Rt[i];
  float acc[4][4];
#pragma unroll
  for (int r = 0; r < 4; ++r)
#pragma unroll
    for (int c = 0; c < 4; ++c) acc[r][c] = 0.f;
  for (int mxc = 0; mxc < N; mxc += 64) {
    __syncthreads();
    {
      int col = tid & 63;
      for (int i = tid >> 6; i < 64; i += 4)
        Tl[i][col] = Tc[(size_t)(mxc + i) * N + tyTile + col];
    }
    __syncthreads();
    for (int i = 0; i < 64; ++i) {
      int mx = mxc + i;
      float ra[4], tb[4];
#pragma unroll
      for (int r = 0; r < 4; ++r)
        ra[r] = Rl[(txTile + txt * 4 + r - mx) & (N - 1)];
#pragma unroll
      for (int c = 0; c < 4; ++c) tb[c] = Tl[i][tyt + 16 * c];
#pragma unroll
      for (int r = 0; r < 4; ++r)
#pragma unroll
        for (int c = 0; c < 4; ++c) acc[r][c] += ra[r] * tb[c];
    }
  }
  float scc = Sc[ch * 4 + 0], scs = Sc[ch * 4 + 1];
  float ssc = Sc[ch * 4 + 2], sss = Sc[ch * 4 + 3];
  float a = PI_F / (float)S;
  float* Yc = Y + (size_t)ch * N * N;
#pragma unroll
  for (int r = 0; r < 4; ++r) {
    int tx = txTile + txt * 4 + r;
    float sxv, cxv;
    sincosf(a * (float)(tx & (2 * S - 1)), &sxv, &cxv);
#pragma unroll
    for (int c = 0; c < 4; ++c) {
      int ty = tyTile + tyt + 16 * c;
      float syv, cyv;
      sincosf(a * (float)(ty & (2 * S - 1)), &syv, &cyv);
      float Q = sxv * syv * scc - sxv * cyv * scs - cxv * syv * ssc + cxv * cyv * sss;
      Yc[(size_t)tx * N + ty] = acc[r][c] - inv * Q;
    }
  }
}

// final correlations: out[b, base+l1*8+l2, p] = sum_{n in coarse} x2[b,l2,n] * Y[b,l1, s*n + p]
__global__ __launch_bounds__(256) void k_corr(const float* __restrict__ x0,
                                              const float* __restrict__ x1,
                                              const float* __restrict__ x2,
                                              const float* __restrict__ y01,
                                              const float* __restrict__ y02,
                                              const float* __restrict__ y12,
                                              float* __restrict__ out) {
  const int pdx[NP] = {0, 0, 0, 1, 1, 2, -1};
  const int pdy[NP] = {0, 1, 2, 0, 1, 0, 1};
  int bid = blockIdx.x;
  int pair, nsplit, segLocal;
  if (bid < 1024)      { pair = 0; nsplit = 8; segLocal = bid; }
  else if (bid < 1280) { pair = 1; nsplit = 2; segLocal = bid - 1024; }
  else if (bid < 1408) { pair = 2; nsplit = 1; segLocal = bid - 1280; }
  else if (bid < 1664) { pair = 3; nsplit = 2; segLocal = bid - 1408; }
  else if (bid < 1792) { pair = 4; nsplit = 1; segLocal = bid - 1664; }
  else                 { pair = 5; nsplit = 1; segLocal = bid - 1792; }
  int split = segLocal >> 7;
  int cb = segLocal & 127;
  int b = cb >> 6;
  int l1 = (cb >> 3) & 7;
  int l2 = cb & 7;
  const float* Y;
  const float* X2;
  int n1, s, base;
  switch (pair) {
    case 0:  Y = x0;  X2 = x0; n1 = 256; s = 1; base = 0;   break;
    case 1:  Y = y01; X2 = x1; n1 = 256; s = 2; base = 64;  break;
    case 2:  Y = y02; X2 = x2; n1 = 256; s = 4; base = 128; break;
    case 3:  Y = x1;  X2 = x1; n1 = 128; s = 1; base = 192; break;
    case 4:  Y = y12; X2 = x2; n1 = 128; s = 2; base = 256; break;
    default: Y = x2;  X2 = x2; n1 = 64;  s = 1; base = 320; break;
  }
  int lgn1 = (n1 == 256) ? 8 : ((n1 == 128) ? 7 : 6);
  int lgs = (s == 4) ? 2 : ((s == 2) ? 1 : 0);
  int lgn2 = lgn1 - lgs;
  int n2 = 1 << lgn2;
  const float* Yc = Y + (size_t)(b * 8 + l1) * n1 * n1;
  const float* Xc = X2 + (size_t)(b * 8 + l2) * n2 * n2;
  int total = n2 * n2;
  int chunk = total / nsplit;
  int start = split * chunk;
  int end = start + chunk;
  float acc[NP];
#pragma unroll
  for (int p = 0; p < NP; ++p) acc[p] = 0.f;
  for (int idx = start + threadIdx.x; idx < end; idx += 256) {
    int nx = idx >> lgn2;
    int ny = idx & (n2 - 1);
    float xv = Xc[idx];
    int fx = nx << lgs;
    int fy = ny << lgs;
#pragma unroll
    for (int p = 0; p < NP; ++p) {
      int tx = (fx + pdx[p]) & (n1 - 1);
      int ty = (fy + pdy[p]) & (n1 - 1);
      acc[p] += xv * Yc[(size_t)tx * n1 + ty];
    }
  }
  __shared__ float red[256];
  float* o = out + ((size_t)b * 384 + base + l1 * 8 + l2) * NP;
#pragma unroll
  for (int p = 0; p < NP; ++p) {
    red[threadIdx.x] = acc[p];
    __syncthreads();
    for (int st = 128; st > 0; st >>= 1) {
      if (threadIdx.x < st) red[threadIdx.x] += red[threadIdx.x + st];
      __syncthreads();
    }
    if (threadIdx.x == 0) atomicAdd(&o[p], red[0]);
    __syncthreads();
  }
}

extern "C" void kernel_launch(void* const* d_in, const int* in_sizes, int n_in,
                              void* d_out, int out_size, void* d_ws, size_t ws_size,
                              hipStream_t stream) {
  const float* X0 = (const float*)d_in[0];  // [2,8,256,256]
  const float* X1 = (const float*)d_in[1];  // [2,8,128,128]
  const float* X2 = (const float*)d_in[2];  // [2,8,64,64]
  float* out = (float*)d_out;               // [2,384,7]
  float* ws = (float*)d_ws;

  float* Y01 = ws;
  float* Y02 = ws + 1048576;
  float* Y12 = ws + 2097152;
  float* T   = ws + 2359296;
  float* R01 = ws + 3407872;
  float* R02 = R01 + 256;
  float* R12 = R02 + 256;
  float* S01 = R12 + 128;
  float* S02 = S01 + 64;
  float* S12 = S02 + 64;

  k_tables<<<1, 256, 0, stream>>>(R01, R02, R12);
  k_proj<<<16, 256, 0, stream>>>(X0, 8, 2, S01);
  k_proj<<<16, 256, 0, stream>>>(X0, 8, 4, S02);
  k_proj<<<16, 256, 0, stream>>>(X1, 7, 2, S12);

  // pair (0,1): lowpass x0 to cutoff 128
  k_conv1<256><<<1024, 256, 0, stream>>>(X0, T, R01);
  k_conv2<256, 2><<<dim3(4, 4, 16), 256, 0, stream>>>(T, Y01, R01, S01,
                                                      1.0f / (128.f * 128.f));
  // pair (0,2): lowpass x0 to cutoff 64
  k_conv1<256><<<1024, 256, 0, stream>>>(X0, T, R02);
  k_conv2<256, 4><<<dim3(4, 4, 16), 256, 0, stream>>>(T, Y02, R02, S02,
                                                      1.0f / (64.f * 64.f));
  // pair (1,2): lowpass x1 to cutoff 64
  k_conv1<128><<<512, 128, 0, stream>>>(X1, T, R12);
  k_conv2<128, 2><<<dim3(2, 2, 16), 256, 0, stream>>>(T, Y12, R12, S12,
                                                      1.0f / (64.f * 64.f));

  hipMemsetAsync(d_out, 0, (size_t)out_size * sizeof(float), stream);
  k_corr<<<1920, 256, 0, stream>>>(X0, X1, X2, Y01, Y02, Y12, out);
}

// Round 2
// 202.729 us; speedup vs baseline: 1.9235x; 1.9235x over previous
//
#include <hip/hip_runtime.h>

#define PI_D 3.14159265358979323846
#define PI_F 3.14159265358979323846f
#define NP 7

// ---- workspace layout (floats) ----
// Y01 @ 0          : 16*256*256 = 1048576
// Y02 @ 1048576    : 1048576
// Y12 @ 2097152    : 16*128*128 = 262144
// T   @ 2359296    : 1048576
// R01 @ 3407872    : 256
// R02 @ 3408128    : 256
// R12 @ 3408384    : 128
// S01 @ 3408512    : 64 (16ch x 4)
// S02 @ 3408576    : 64
// S12 @ 3408640    : 64   -> total 3408704 floats ~= 13.0 MB

__device__ inline float rtab_val(int n, int m2, int t) {
  if (t == 0) return 1.0f;
  double th = PI_D * (double)t / (double)n;
  double v = sin(th * (double)(m2 - 1)) / sin(th) + cos(th * (double)m2);
  return (float)(v / (double)m2);  // scaled by 1/m2 (applied once per axis)
}

__global__ void k_tables(float* __restrict__ R01, float* __restrict__ R02,
                         float* __restrict__ R12, float* __restrict__ Szero) {
  int t = threadIdx.x;
  if (t < 256) {
    R01[t] = rtab_val(256, 128, t);
    R02[t] = rtab_val(256, 64, t);
  }
  if (t < 128) R12[t] = rtab_val(128, 64, t);
  if (t < 192) Szero[t] = 0.f;  // zero S01|S02|S12 (contiguous 192 floats)
}

// Fused Nyquist-correction projections: Scc,Scs,Ssc,Sss per channel.
// grid: [0,256)   -> X0, s=2 -> S01  (16 ch x 16 splits)
//       [256,512) -> X0, s=4 -> S02  (16 ch x 16 splits)
//       [512,576) -> X1, s=2 -> S12  (16 ch x 4 splits)
__global__ __launch_bounds__(256) void k_proj_all(const float* __restrict__ X0,
                                                  const float* __restrict__ X1,
                                                  float* __restrict__ S01,
                                                  float* __restrict__ S02,
                                                  float* __restrict__ S12) {
  int bid = blockIdx.x;
  const float* X;
  float* S;
  int lg, s, ch, split, nsplit;
  if (bid < 256) {
    X = X0; S = S01; lg = 8; s = 2; ch = bid >> 4; split = bid & 15; nsplit = 16;
  } else if (bid < 512) {
    bid -= 256;
    X = X0; S = S02; lg = 8; s = 4; ch = bid >> 4; split = bid & 15; nsplit = 16;
  } else {
    bid -= 512;
    X = X1; S = S12; lg = 7; s = 2; ch = bid >> 2; split = bid & 3; nsplit = 4;
  }
  int n = 1 << lg;
  int per = 2 * s;  // 4 or 8
  float a = PI_F / (float)s;
  float ct[8], st[8];
#pragma unroll
  for (int k = 0; k < 8; ++k) {
    float sv, cv;
    sincosf(a * (float)(k & (per - 1)), &sv, &cv);
    ct[k] = cv;
    st[k] = sv;
  }
  const float* x = X + (size_t)ch * n * n;
  int total = n * n;
  int chunk = total / nsplit;
  int start = split * chunk;
  int end = start + chunk;
  float cc = 0.f, cs = 0.f, sc = 0.f, ss = 0.f;
  for (int idx = start + threadIdx.x; idx < end; idx += 256) {
    int mx = (idx >> lg) & 7;
    int my = idx & 7;
    float cxv = ct[mx & (per - 1)], sxv = st[mx & (per - 1)];
    float cyv = ct[my & (per - 1)], syv = st[my & (per - 1)];
    float v = x[idx];
    cc += v * cxv * cyv;
    cs += v * cxv * syv;
    sc += v * sxv * cyv;
    ss += v * sxv * syv;
  }
  // wave-level shuffle reduce, then cross-wave via LDS
  float vals[4] = {cc, cs, sc, ss};
  __shared__ float red[4][4];
  int lane = threadIdx.x & 63;
  int wv = threadIdx.x >> 6;
#pragma unroll
  for (int j = 0; j < 4; ++j) {
    float v = vals[j];
#pragma unroll
    for (int off = 32; off > 0; off >>= 1) v += __shfl_down(v, off, 64);
    if (lane == 0) red[wv][j] = v;
  }
  __syncthreads();
  if (threadIdx.x < 4) {
    float v = red[0][threadIdx.x] + red[1][threadIdx.x] + red[2][threadIdx.x] +
              red[3][threadIdx.x];
    atomicAdd(&S[ch * 4 + threadIdx.x], v);
  }
}

// circular conv along contiguous (last) axis: T[row, t] = sum_my R[(t-my)&(N-1)] * In[row, my]
template <int N>
__global__ __launch_bounds__(N) void k_conv1(const float* __restrict__ In,
                                             float* __restrict__ Out,
                                             const float* __restrict__ Rt) {
  __shared__ float Rl[N];
  __shared__ float Xl[4][N];
  int t = threadIdx.x;
  size_t row0 = (size_t)blockIdx.x * 4;
  Rl[t] = Rt[t];
#pragma unroll
  for (int r = 0; r < 4; ++r) Xl[r][t] = In[(row0 + r) * N + t];
  __syncthreads();
  float a0 = 0.f, a1 = 0.f, a2 = 0.f, a3 = 0.f;
#pragma unroll 4
  for (int my = 0; my < N; ++my) {
    float rv = Rl[(t - my) & (N - 1)];
    a0 += rv * Xl[0][my];
    a1 += rv * Xl[1][my];
    a2 += rv * Xl[2][my];
    a3 += rv * Xl[3][my];
  }
  Out[(row0 + 0) * N + t] = a0;
  Out[(row0 + 1) * N + t] = a1;
  Out[(row0 + 2) * N + t] = a2;
  Out[(row0 + 3) * N + t] = a3;
}

// circular conv along first axis of each NxN channel matrix + Nyquist-correction epilogue
template <int N, int S>
__global__ __launch_bounds__(256) void k_conv2(const float* __restrict__ T,
                                               float* __restrict__ Y,
                                               const float* __restrict__ Rt,
                                               const float* __restrict__ Sc,
                                               float inv) {
  __shared__ float Rl[N];
  __shared__ float Tl[64][65];
  int tid = threadIdx.x;
  int tyt = tid & 15;
  int txt = tid >> 4;
  int txTile = blockIdx.x * 64;
  int tyTile = blockIdx.y * 64;
  int ch = blockIdx.z;
  const float* Tc = T + (size_t)ch * N * N;
  for (int i = tid; i < N; i += 256) Rl[i] = Rt[i];
  float acc[4][4];
#pragma unroll
  for (int r = 0; r < 4; ++r)
#pragma unroll
    for (int c = 0; c < 4; ++c) acc[r][c] = 0.f;
  for (int mxc = 0; mxc < N; mxc += 64) {
    __syncthreads();
    {
      int col = tid & 63;
      for (int i = tid >> 6; i < 64; i += 4)
        Tl[i][col] = Tc[(size_t)(mxc + i) * N + tyTile + col];
    }
    __syncthreads();
    for (int i = 0; i < 64; ++i) {
      int mx = mxc + i;
      float ra[4], tb[4];
#pragma unroll
      for (int r = 0; r < 4; ++r)
        ra[r] = Rl[(txTile + txt * 4 + r - mx) & (N - 1)];
#pragma unroll
      for (int c = 0; c < 4; ++c) tb[c] = Tl[i][tyt + 16 * c];
#pragma unroll
      for (int r = 0; r < 4; ++r)
#pragma unroll
        for (int c = 0; c < 4; ++c) acc[r][c] += ra[r] * tb[c];
    }
  }
  float scc = Sc[ch * 4 + 0], scs = Sc[ch * 4 + 1];
  float ssc = Sc[ch * 4 + 2], sss = Sc[ch * 4 + 3];
  float a = PI_F / (float)S;
  float* Yc = Y + (size_t)ch * N * N;
#pragma unroll
  for (int r = 0; r < 4; ++r) {
    int tx = txTile + txt * 4 + r;
    float sxv, cxv;
    sincosf(a * (float)(tx & (2 * S - 1)), &sxv, &cxv);
#pragma unroll
    for (int c = 0; c < 4; ++c) {
      int ty = tyTile + tyt + 16 * c;
      float syv, cyv;
      sincosf(a * (float)(ty & (2 * S - 1)), &syv, &cyv);
      float Q = sxv * syv * scc - sxv * cyv * scs - cxv * syv * ssc + cxv * cyv * sss;
      Yc[(size_t)tx * N + ty] = acc[r][c] - inv * Q;
    }
  }
}

// final correlations: out[b, base+l1*8+l2, p] = sum_{n in coarse} x2[b,l2,n] * Y[b,l1, s*n + p]
__global__ __launch_bounds__(256) void k_corr(const float* __restrict__ x0,
                                              const float* __restrict__ x1,
                                              const float* __restrict__ x2,
                                              const float* __restrict__ y01,
                                              const float* __restrict__ y02,
                                              const float* __restrict__ y12,
                                              float* __restrict__ out) {
  const int pdx[NP] = {0, 0, 0, 1, 1, 2, -1};
  const int pdy[NP] = {0, 1, 2, 0, 1, 0, 1};
  int bid = blockIdx.x;
  int pair, nsplit, segLocal;
  if (bid < 1024)      { pair = 0; nsplit = 8; segLocal = bid; }
  else if (bid < 1280) { pair = 1; nsplit = 2; segLocal = bid - 1024; }
  else if (bid < 1408) { pair = 2; nsplit = 1; segLocal = bid - 1280; }
  else if (bid < 1664) { pair = 3; nsplit = 2; segLocal = bid - 1408; }
  else if (bid < 1792) { pair = 4; nsplit = 1; segLocal = bid - 1664; }
  else                 { pair = 5; nsplit = 1; segLocal = bid - 1792; }
  int split = segLocal >> 7;
  int cb = segLocal & 127;
  int b = cb >> 6;
  int l1 = (cb >> 3) & 7;
  int l2 = cb & 7;
  const float* Y;
  const float* X2;
  int n1, s, base;
  switch (pair) {
    case 0:  Y = x0;  X2 = x0; n1 = 256; s = 1; base = 0;   break;
    case 1:  Y = y01; X2 = x1; n1 = 256; s = 2; base = 64;  break;
    case 2:  Y = y02; X2 = x2; n1 = 256; s = 4; base = 128; break;
    case 3:  Y = x1;  X2 = x1; n1 = 128; s = 1; base = 192; break;
    case 4:  Y = y12; X2 = x2; n1 = 128; s = 2; base = 256; break;
    default: Y = x2;  X2 = x2; n1 = 64;  s = 1; base = 320; break;
  }
  int lgn1 = (n1 == 256) ? 8 : ((n1 == 128) ? 7 : 6);
  int lgs = (s == 4) ? 2 : ((s == 2) ? 1 : 0);
  int lgn2 = lgn1 - lgs;
  int n2 = 1 << lgn2;
  const float* Yc = Y + (size_t)(b * 8 + l1) * n1 * n1;
  const float* Xc = X2 + (size_t)(b * 8 + l2) * n2 * n2;
  int total = n2 * n2;
  int chunk = total / nsplit;
  int start = split * chunk;
  int end = start + chunk;
  float acc[NP];
#pragma unroll
  for (int p = 0; p < NP; ++p) acc[p] = 0.f;
  for (int idx = start + threadIdx.x; idx < end; idx += 256) {
    int nx = idx >> lgn2;
    int ny = idx & (n2 - 1);
    float xv = Xc[idx];
    int fx = nx << lgs;
    int fy = ny << lgs;
#pragma unroll
    for (int p = 0; p < NP; ++p) {
      int tx = (fx + pdx[p]) & (n1 - 1);
      int ty = (fy + pdy[p]) & (n1 - 1);
      acc[p] += xv * Yc[(size_t)tx * n1 + ty];
    }
  }
  __shared__ float red[4][NP];
  int lane = threadIdx.x & 63;
  int wv = threadIdx.x >> 6;
#pragma unroll
  for (int p = 0; p < NP; ++p) {
    float v = acc[p];
#pragma unroll
    for (int off = 32; off > 0; off >>= 1) v += __shfl_down(v, off, 64);
    if (lane == 0) red[wv][p] = v;
  }
  __syncthreads();
  float* o = out + ((size_t)b * 384 + base + l1 * 8 + l2) * NP;
  if (threadIdx.x < NP) {
    float v = red[0][threadIdx.x] + red[1][threadIdx.x] + red[2][threadIdx.x] +
              red[3][threadIdx.x];
    atomicAdd(&o[threadIdx.x], v);
  }
}

extern "C" void kernel_launch(void* const* d_in, const int* in_sizes, int n_in,
                              void* d_out, int out_size, void* d_ws, size_t ws_size,
                              hipStream_t stream) {
  const float* X0 = (const float*)d_in[0];  // [2,8,256,256]
  const float* X1 = (const float*)d_in[1];  // [2,8,128,128]
  const float* X2 = (const float*)d_in[2];  // [2,8,64,64]
  float* out = (float*)d_out;               // [2,384,7]
  float* ws = (float*)d_ws;

  float* Y01 = ws;
  float* Y02 = ws + 1048576;
  float* Y12 = ws + 2097152;
  float* T   = ws + 2359296;
  float* R01 = ws + 3407872;
  float* R02 = R01 + 256;
  float* R12 = R02 + 256;
  float* S01 = R12 + 128;
  float* S02 = S01 + 64;
  float* S12 = S02 + 64;

  k_tables<<<1, 256, 0, stream>>>(R01, R02, R12, S01);
  k_proj_all<<<576, 256, 0, stream>>>(X0, X1, S01, S02, S12);

  // pair (0,1): lowpass x0 to cutoff 128
  k_conv1<256><<<1024, 256, 0, stream>>>(X0, T, R01);
  k_conv2<256, 2><<<dim3(4, 4, 16), 256, 0, stream>>>(T, Y01, R01, S01,
                                                      1.0f / (128.f * 128.f));
  // pair (0,2): lowpass x0 to cutoff 64
  k_conv1<256><<<1024, 256, 0, stream>>>(X0, T, R02);
  k_conv2<256, 4><<<dim3(4, 4, 16), 256, 0, stream>>>(T, Y02, R02, S02,
                                                      1.0f / (64.f * 64.f));
  // pair (1,2): lowpass x1 to cutoff 64
  k_conv1<128><<<512, 128, 0, stream>>>(X1, T, R12);
  k_conv2<128, 2><<<dim3(2, 2, 16), 256, 0, stream>>>(T, Y12, R12, S12,
                                                      1.0f / (64.f * 64.f));

  hipMemsetAsync(d_out, 0, (size_t)out_size * sizeof(float), stream);
  k_corr<<<1920, 256, 0, stream>>>(X0, X1, X2, Y01, Y02, Y12, out);
}